// Round 5
// baseline (83.532 us; speedup 1.0000x reference)
//
#include <hip/hip_runtime.h>

// RBFNN L1-distance, round 5: split-K=8, 4 independent blocks per CU.
// k_sim: 1024 blocks x 256 threads (__launch_bounds__(256,4) -> VGPR<=128,
//   4 blocks/CU = 4 waves/SIMD from independent blocks -> uncorrelated stalls).
//   Each block: 64x64 output tile over K=64 window. Single staging phase, one
//   barrier, then pure compute. LDS rows padded to 36 dwords (stride 144 B):
//   consecutive rows shift 4 banks -> 2-way aliasing (free), and granule
//   offsets fold into ds_read_b128 immediate offsets (zero addr VALU in loop).
//   f16 math: v_pk_sub_f16 + v_and(abs) + v_dot2_f32_f16, f32 accumulate.
// k_red: sum 8 partial planes -> S, per-block max -> bmax[512].
// k_out: global max, out = beta * (max*1.001 - sim) in place.

typedef _Float16 h2 __attribute__((ext_vector_type(2)));
typedef float f4 __attribute__((ext_vector_type(4)));
typedef unsigned int u32x4 __attribute__((ext_vector_type(4)));

#define DIM_K 512
#define DIM_O 512
#define NSPLIT 8
#define KW (DIM_K / NSPLIT)      // 64 k per block
#define LROW 36                  // dwords per LDS row: 32 data + 4 pad
#define PSTRIDE (1024 * 512)     // one partial plane, floats
#define W_DIST 1.001f

__device__ __forceinline__ h2 as_h2(unsigned int u){ h2 r; __builtin_memcpy(&r,&u,4); return r; }
__device__ __forceinline__ unsigned int cvt2(float a, float b){
    auto h = __builtin_amdgcn_cvt_pkrtz(a, b);  // __fp16x2 -> move bits
    unsigned int r; __builtin_memcpy(&r, &h, 4); return r;
}

__global__ __launch_bounds__(256, 4) void k_sim(const float* __restrict__ X,
                                                const float* __restrict__ C,
                                                float* __restrict__ P)
{
    __shared__ __align__(16) unsigned int xs[64 * LROW]; // 9216 B
    __shared__ __align__(16) unsigned int cs[64 * LROW]; // 9216 B
    const int tid = threadIdx.x;
    const int b = blockIdx.x;
    const int ks = b & 7;          // k slice
    const int ct = (b >> 3) & 7;   // 8 col tiles
    const int rt = b >> 6;         // 16 row tiles
    const int row0 = rt * 64, col0 = ct * 64, kb = ks * KW;

    // ---- stage both 64x64 f32 tiles as f16 (one barrier) ----
    {
        const int row = tid >> 2, q = tid & 3;           // q = 16-float chunk
        const float* xg = X + (row0 + row) * DIM_K + kb + q * 16;
        f4 a0 = *(const f4*)xg, a1 = *(const f4*)(xg + 4),
           a2 = *(const f4*)(xg + 8), a3 = *(const f4*)(xg + 12);
        u32x4 w0, w1;
        w0[0]=cvt2(a0.x,a0.y); w0[1]=cvt2(a0.z,a0.w); w0[2]=cvt2(a1.x,a1.y); w0[3]=cvt2(a1.z,a1.w);
        w1[0]=cvt2(a2.x,a2.y); w1[1]=cvt2(a2.z,a2.w); w1[2]=cvt2(a3.x,a3.y); w1[3]=cvt2(a3.z,a3.w);
        *(u32x4*)&xs[row * LROW + q * 8]     = w0;
        *(u32x4*)&xs[row * LROW + q * 8 + 4] = w1;
        const float* cg = C + (col0 + row) * DIM_K + kb + q * 16;
        a0 = *(const f4*)cg; a1 = *(const f4*)(cg + 4);
        a2 = *(const f4*)(cg + 8); a3 = *(const f4*)(cg + 12);
        w0[0]=cvt2(a0.x,a0.y); w0[1]=cvt2(a0.z,a0.w); w0[2]=cvt2(a1.x,a1.y); w0[3]=cvt2(a1.z,a1.w);
        w1[0]=cvt2(a2.x,a2.y); w1[1]=cvt2(a2.z,a2.w); w1[2]=cvt2(a3.x,a3.y); w1[3]=cvt2(a3.z,a3.w);
        *(u32x4*)&cs[row * LROW + q * 8]     = w0;
        *(u32x4*)&cs[row * LROW + q * 8 + 4] = w1;
    }
    __syncthreads();

    const int rb = (tid >> 4) * 4;  // rows rb..rb+3
    const int tc = tid & 15;        // cols tc + 16j
    float acc[4][4] = {};
    const h2 one2 = {(_Float16)1.f, (_Float16)1.f};

    // base pointers; g offsets become ds_read immediate offsets
    const unsigned int* xb0 = &xs[(rb + 0) * LROW];
    const unsigned int* xb1 = &xs[(rb + 1) * LROW];
    const unsigned int* xb2 = &xs[(rb + 2) * LROW];
    const unsigned int* xb3 = &xs[(rb + 3) * LROW];
    const unsigned int* cb0 = &cs[(tc +  0) * LROW];
    const unsigned int* cb1 = &cs[(tc + 16) * LROW];
    const unsigned int* cb2 = &cs[(tc + 32) * LROW];
    const unsigned int* cb3 = &cs[(tc + 48) * LROW];

#pragma unroll
    for (int g = 0; g < 8; ++g) {   // 8 granules x 8 k
        u32x4 xr[4], cr[4];
        xr[0] = *(const u32x4*)(xb0 + g * 4);
        xr[1] = *(const u32x4*)(xb1 + g * 4);
        xr[2] = *(const u32x4*)(xb2 + g * 4);
        xr[3] = *(const u32x4*)(xb3 + g * 4);
        cr[0] = *(const u32x4*)(cb0 + g * 4);
        cr[1] = *(const u32x4*)(cb1 + g * 4);
        cr[2] = *(const u32x4*)(cb2 + g * 4);
        cr[3] = *(const u32x4*)(cb3 + g * 4);
#pragma unroll
        for (int k2 = 0; k2 < 4; ++k2) {
#pragma unroll
            for (int i = 0; i < 4; ++i) {
                const h2 a = as_h2(xr[i][k2]);
#pragma unroll
                for (int j = 0; j < 4; ++j) {
                    h2 d = a - as_h2(cr[j][k2]);           // v_pk_sub_f16
                    unsigned int du; __builtin_memcpy(&du, &d, 4);
                    h2 ad = as_h2(du & 0x7fff7fffu);       // abs both halves
                    acc[i][j] = __builtin_amdgcn_fdot2(ad, one2, acc[i][j], false);
                }
            }
        }
    }

    // ---- write partial tile (16-lane contiguous stores) ----
    float* Pk = P + ks * PSTRIDE;
#pragma unroll
    for (int i = 0; i < 4; ++i) {
        const int row = row0 + rb + i;
#pragma unroll
        for (int j = 0; j < 4; ++j)
            Pk[row * DIM_O + col0 + tc + 16 * j] = acc[i][j];
    }
}

__global__ __launch_bounds__(256) void k_red(const float* __restrict__ P,
                                             float* __restrict__ S,
                                             float* __restrict__ bmax)
{
    const int tid = threadIdx.x;
    const int f = blockIdx.x * 256 + tid;  // f4 index, 131072 total
    const f4* P4 = (const f4*)P;
    const int q = PSTRIDE / 4;
    f4 s = P4[f];
#pragma unroll
    for (int p = 1; p < NSPLIT; ++p)
        s += P4[f + p * q];
    ((f4*)S)[f] = s;
    float m = fmaxf(fmaxf(s.x, s.y), fmaxf(s.z, s.w));
#pragma unroll
    for (int off = 32; off > 0; off >>= 1)
        m = fmaxf(m, __shfl_xor(m, off, 64));
    __shared__ float wm[4];
    if ((tid & 63) == 0) wm[tid >> 6] = m;
    __syncthreads();
    if (tid == 0)
        bmax[blockIdx.x] = fmaxf(fmaxf(wm[0], wm[1]), fmaxf(wm[2], wm[3]));
}

__global__ __launch_bounds__(256) void k_out(float* __restrict__ S,
                                             const float* __restrict__ beta,
                                             const float* __restrict__ bmax)
{
    const int tid = threadIdx.x;
    const int lane = tid & 63;
    float m = 0.f;
#pragma unroll
    for (int i = 0; i < 8; ++i)            // 512 block maxes
        m = fmaxf(m, bmax[lane + 64 * i]);
#pragma unroll
    for (int off = 32; off > 0; off >>= 1)
        m = fmaxf(m, __shfl_xor(m, off, 64));
    const float shift = m * W_DIST;

    const int f = blockIdx.x * 256 + tid;  // f4 index
    f4 s = ((const f4*)S)[f];
    f4 b = ((const f4*)beta)[f & 127];
    f4 r;
    r.x = b.x * (shift - s.x);
    r.y = b.y * (shift - s.y);
    r.z = b.z * (shift - s.z);
    r.w = b.w * (shift - s.w);
    ((f4*)S)[f] = r;
}

extern "C" void kernel_launch(void* const* d_in, const int* in_sizes, int n_in,
                              void* d_out, int out_size, void* d_ws, size_t ws_size,
                              hipStream_t stream) {
    const float* X = (const float*)d_in[0];
    const float* C = (const float*)d_in[1];
    const float* beta = (const float*)d_in[2];
    float* S = (float*)d_out;
    float* P = (float*)d_ws;                       // 8 x 2 MB partial planes
    float* bmax = (float*)d_ws + NSPLIT * PSTRIDE; // 512 floats after partials
    k_sim<<<1024, 256, 0, stream>>>(X, C, P);
    k_red<<<512, 256, 0, stream>>>(P, S, bmax);
    k_out<<<512, 256, 0, stream>>>(S, beta, bmax);
}

// Round 6
// 80.778 us; speedup vs baseline: 1.0341x; 1.0341x over previous
//
#include <hip/hip_runtime.h>

// RBFNN L1-distance, round 6: f32 discriminating experiment (H1: packed-f16
// dot2 path is slow on CDNA4). Identical structure to R5 (split-K=8, 64x64
// tiles, 1024 blocks x 256 thr, 4 blocks/CU), but all-f32:
//   - staging: straight f32 copy global->LDS (no cvt_pkrtz)
//   - inner loop: v_sub_f32 + v_add_f32 with abs modifier (full-rate VOP3 only)
//   - LDS rows padded to 68 dwords (64 data + 4): rows shift 4 banks -> 2-way
//     aliasing (free), granule offsets fold into ds_read_b128 immediates.
// k_red: sum 8 partial planes -> S, per-block max -> bmax[512].
// k_out: global max, out = beta * (max*1.001 - sim) in place.

typedef float f4 __attribute__((ext_vector_type(4)));

#define DIM_K 512
#define DIM_O 512
#define NSPLIT 8
#define KW (DIM_K / NSPLIT)      // 64 k per block
#define LROW 68                  // floats per LDS row: 64 data + 4 pad
#define PSTRIDE (1024 * 512)     // one partial plane, floats
#define W_DIST 1.001f

__global__ __launch_bounds__(256, 4) void k_sim(const float* __restrict__ X,
                                                const float* __restrict__ C,
                                                float* __restrict__ P)
{
    __shared__ __align__(16) float xs[64 * LROW]; // 17408 B
    __shared__ __align__(16) float cs[64 * LROW]; // 17408 B
    const int tid = threadIdx.x;
    const int b = blockIdx.x;
    const int ks = b & 7;          // k slice
    const int ct = (b >> 3) & 7;   // 8 col tiles
    const int rt = b >> 6;         // 16 row tiles
    const int row0 = rt * 64, col0 = ct * 64, kb = ks * KW;

    // ---- stage both 64x64 f32 tiles (one barrier) ----
    {
        const int row = tid >> 2, q = tid & 3;   // q = 16-float chunk
        const float* xg = X + (row0 + row) * DIM_K + kb + q * 16;
        float* xd = &xs[row * LROW + q * 16];
        *(f4*)(xd + 0)  = *(const f4*)(xg + 0);
        *(f4*)(xd + 4)  = *(const f4*)(xg + 4);
        *(f4*)(xd + 8)  = *(const f4*)(xg + 8);
        *(f4*)(xd + 12) = *(const f4*)(xg + 12);
        const float* cg = C + (col0 + row) * DIM_K + kb + q * 16;
        float* cd = &cs[row * LROW + q * 16];
        *(f4*)(cd + 0)  = *(const f4*)(cg + 0);
        *(f4*)(cd + 4)  = *(const f4*)(cg + 4);
        *(f4*)(cd + 8)  = *(const f4*)(cg + 8);
        *(f4*)(cd + 12) = *(const f4*)(cg + 12);
    }
    __syncthreads();

    const int rb = (tid >> 4) * 4;  // rows rb..rb+3
    const int tc = tid & 15;        // cols tc + 16j
    float acc[4][4] = {};

    const float* xb0 = &xs[(rb + 0) * LROW];
    const float* xb1 = &xs[(rb + 1) * LROW];
    const float* xb2 = &xs[(rb + 2) * LROW];
    const float* xb3 = &xs[(rb + 3) * LROW];
    const float* cb0 = &cs[(tc +  0) * LROW];
    const float* cb1 = &cs[(tc + 16) * LROW];
    const float* cb2 = &cs[(tc + 32) * LROW];
    const float* cb3 = &cs[(tc + 48) * LROW];

#pragma unroll
    for (int g = 0; g < 16; ++g) {  // 16 granules x 4 k
        f4 xr[4], cr[4];
        xr[0] = *(const f4*)(xb0 + g * 4);
        xr[1] = *(const f4*)(xb1 + g * 4);
        xr[2] = *(const f4*)(xb2 + g * 4);
        xr[3] = *(const f4*)(xb3 + g * 4);
        cr[0] = *(const f4*)(cb0 + g * 4);
        cr[1] = *(const f4*)(cb1 + g * 4);
        cr[2] = *(const f4*)(cb2 + g * 4);
        cr[3] = *(const f4*)(cb3 + g * 4);
#pragma unroll
        for (int k2 = 0; k2 < 4; ++k2) {
#pragma unroll
            for (int i = 0; i < 4; ++i) {
                const float a = xr[i][k2];
#pragma unroll
                for (int j = 0; j < 4; ++j) {
                    // v_sub_f32 + v_add_f32 with |.| folded as src modifier
                    acc[i][j] += __builtin_fabsf(a - cr[j][k2]);
                }
            }
        }
    }

    // ---- write partial tile (16-lane contiguous stores) ----
    float* Pk = P + ks * PSTRIDE;
#pragma unroll
    for (int i = 0; i < 4; ++i) {
        const int row = row0 + rb + i;
#pragma unroll
        for (int j = 0; j < 4; ++j)
            Pk[row * DIM_O + col0 + tc + 16 * j] = acc[i][j];
    }
}

__global__ __launch_bounds__(256) void k_red(const float* __restrict__ P,
                                             float* __restrict__ S,
                                             float* __restrict__ bmax)
{
    const int tid = threadIdx.x;
    const int f = blockIdx.x * 256 + tid;  // f4 index, 131072 total
    const f4* P4 = (const f4*)P;
    const int q = PSTRIDE / 4;
    f4 s = P4[f];
#pragma unroll
    for (int p = 1; p < NSPLIT; ++p)
        s += P4[f + p * q];
    ((f4*)S)[f] = s;
    float m = fmaxf(fmaxf(s.x, s.y), fmaxf(s.z, s.w));
#pragma unroll
    for (int off = 32; off > 0; off >>= 1)
        m = fmaxf(m, __shfl_xor(m, off, 64));
    __shared__ float wm[4];
    if ((tid & 63) == 0) wm[tid >> 6] = m;
    __syncthreads();
    if (tid == 0)
        bmax[blockIdx.x] = fmaxf(fmaxf(wm[0], wm[1]), fmaxf(wm[2], wm[3]));
}

__global__ __launch_bounds__(256) void k_out(float* __restrict__ S,
                                             const float* __restrict__ beta,
                                             const float* __restrict__ bmax)
{
    const int tid = threadIdx.x;
    const int lane = tid & 63;
    float m = 0.f;
#pragma unroll
    for (int i = 0; i < 8; ++i)            // 512 block maxes
        m = fmaxf(m, bmax[lane + 64 * i]);
#pragma unroll
    for (int off = 32; off > 0; off >>= 1)
        m = fmaxf(m, __shfl_xor(m, off, 64));
    const float shift = m * W_DIST;

    const int f = blockIdx.x * 256 + tid;  // f4 index
    f4 s = ((const f4*)S)[f];
    f4 b = ((const f4*)beta)[f & 127];
    f4 r;
    r.x = b.x * (shift - s.x);
    r.y = b.y * (shift - s.y);
    r.z = b.z * (shift - s.z);
    r.w = b.w * (shift - s.w);
    ((f4*)S)[f] = r;
}

extern "C" void kernel_launch(void* const* d_in, const int* in_sizes, int n_in,
                              void* d_out, int out_size, void* d_ws, size_t ws_size,
                              hipStream_t stream) {
    const float* X = (const float*)d_in[0];
    const float* C = (const float*)d_in[1];
    const float* beta = (const float*)d_in[2];
    float* S = (float*)d_out;
    float* P = (float*)d_ws;                       // 8 x 2 MB partial planes
    float* bmax = (float*)d_ws + NSPLIT * PSTRIDE; // 512 floats after partials
    k_sim<<<1024, 256, 0, stream>>>(X, C, P);
    k_red<<<512, 256, 0, stream>>>(P, S, bmax);
    k_out<<<512, 256, 0, stream>>>(S, beta, bmax);
}